// Round 25
// baseline (46.332 us; speedup 1.0000x reference)
//
#include <hip/hip_runtime.h>

// Problem constants: B=128, n=64, E=65536, K=16, D=64, e_full=524288
#define EF      524288
#define NEDGE   65536
#define KDIM    16
#define DDIM    64
#define TPW     2
#define PVBLK   (EF / (32 * TPW) / 4)   // 2048 blocks, 4 waves each
#define LSTR    68
#define NTILE   (EF / 32)               // 16384 slot-tiles of 32 rows
#define CAP     64                      // edge-list capacity per tile (avg 4)
#define PF      8                       // edge rows prefetched per tile

typedef float vfloat4 __attribute__((ext_vector_type(4)));
typedef short bf16x8  __attribute__((ext_vector_type(8)));
typedef float f32x16  __attribute__((ext_vector_type(16)));

__device__ __forceinline__ short f2bf(float f) {   // f32 -> bf16, RNE
    unsigned u = __float_as_uint(f);
    return (short)((u + 0x7FFFu + ((u >> 16) & 1u)) >> 16);
}

__device__ __forceinline__ long edge_slot(const int* ei, int e) {
    int r = ei[e];
    int c = ei[NEDGE + e];
    return ((long)(r >> 6) << 12) + ((long)(r & 63) << 6) + (long)(c & 63);
}

// ws layout: [0,64K) tile counts | [64K,64K+4M) lists | ovf_cnt | ovf list
#define WS_CNT_OFF   0
#define WS_LIST_OFF  (64 * 1024)
#define WS_OVFC_OFF  (WS_LIST_OFF + NTILE * CAP * 4)
#define WS_OVFL_OFF  (WS_OVFC_OFF + 4)
#define WS_NEED      (WS_OVFL_OFF + NEDGE * 4)

// ---------------------------------------------------------------------------
__global__ __launch_bounds__(256) void zero_cnt(unsigned* __restrict__ cnt,
                                                unsigned* __restrict__ ovfc) {
    int gid = blockIdx.x * 256 + threadIdx.x;   // 16384 threads
    cnt[gid] = 0u;
    if (gid == 0) *ovfc = 0u;
}

// ---------------------------------------------------------------------------
__global__ __launch_bounds__(256) void bin_edges(const int* __restrict__ ei,
                                                 unsigned* __restrict__ cnt,
                                                 int* __restrict__ list,
                                                 unsigned* __restrict__ ovfc,
                                                 int* __restrict__ ovfl) {
    int e = blockIdx.x * 256 + threadIdx.x;     // NEDGE threads
    long slot = edge_slot(ei, e);
    int tile = (int)(slot >> 5);
    int row  = (int)(slot & 31);
    unsigned pos = atomicAdd(&cnt[tile], 1u);
    if (pos < CAP) list[tile * CAP + pos] = (e << 5) | row;
    else           ovfl[atomicAdd(ovfc, 1u)] = e;
}

// ---------------------------------------------------------------------------
// pv_fused v6 = R19's v5 + (a) empty-tile fast path: ec==0 tiles store acc
// directly from registers (the 25.5us R14-probe pattern, no LDS round-trip);
// (b) vpre/ea junk prefetch skipped when the wave's tile is empty
// (wave-uniform branch; removes ~33MB of junk gather for empty tiles).
// Edge tiles keep the proven prologue-prefetch + LDS-merge path.
// ---------------------------------------------------------------------------
__global__ __launch_bounds__(256) void pv_fused(const float* __restrict__ pv,
                                                const float* __restrict__ W,
                                                const float* __restrict__ ea,
                                                const unsigned* __restrict__ cnt,
                                                const int* __restrict__ list,
                                                float* __restrict__ out,
                                                float* __restrict__ outv) {
    __shared__ float lds[4][32 * LSTR];
    int tid = threadIdx.x;
    int wv  = tid >> 6;
    int l   = tid & 63;
    int n   = l & 31;
    int kh  = l >> 5;
    long j0 = ((long)blockIdx.x * 4 + wv) * (32 * TPW);
    int tile0 = (int)(j0 >> 5);

    // ---- issue-early: cnt (2), list (16, unconditional) ----
    unsigned ec0 = cnt[tile0];
    unsigned ec1 = cnt[tile0 + 1];
    int pk0[PF], pk1[PF];
#pragma unroll
    for (int i = 0; i < PF; ++i) {
        pk0[i] = list[(long)tile0 * CAP + i];
        pk1[i] = list[(long)(tile0 + 1) * CAP + i];
    }

    // ---- idx fill for this block's 256 rows (independent; hides latency) ----
    {
        int j = blockIdx.x * 256 + tid;         // [0, EF)
        int g = j >> 12;
        int rem = j & 4095;
        out[j]      = (float)((g << 6) + (rem >> 6));
        out[EF + j] = (float)((g << 6) + (rem & 63));
    }

    // ---- ea rows: unconditional-clamped, but only if tile non-empty ----
    float vpre0[PF], vpre1[PF];
#pragma unroll
    for (int i = 0; i < PF; ++i) {
        if (ec0) {
            unsigned e0 = ((unsigned)pk0[i] >> 5) & (NEDGE - 1);
            vpre0[i] = ea[(long)e0 * DDIM + l];
        }
        if (ec1) {
            unsigned e1 = ((unsigned)pk1[i] >> 5) & (NEDGE - 1);
            vpre1[i] = ea[(long)e1 * DDIM + l];
        }
    }

    unsigned ecc0 = ec0 > CAP ? CAP : ec0;
    unsigned ecc1 = ec1 > CAP ? CAP : ec1;
    unsigned ep0 = ecc0 > PF ? PF : ecc0;
    unsigned ep1 = ecc1 > PF ? PF : ecc1;

    // ---- pv fragments (both tiles) ----
    const float4* bp0 = reinterpret_cast<const float4*>(pv + (j0 + n) * KDIM + kh * 8);
    const float4* bp1 = reinterpret_cast<const float4*>(pv + (j0 + 32 + n) * KDIM + kh * 8);
    float4 ba0 = bp0[0], bb0 = bp0[1], ba1 = bp1[0], bb1 = bp1[1];

    // ---- W fragments (L1-resident) ----
    const float4* wp0 = reinterpret_cast<const float4*>(W + n * KDIM + kh * 8);
    const float4* wp1 = reinterpret_cast<const float4*>(W + (32 + n) * KDIM + kh * 8);
    float4 w0a = wp0[0], w0b = wp0[1], w1a = wp1[0], w1b = wp1[1];
    bf16x8 xa0, xa1;
    xa0[0]=f2bf(w0a.x); xa0[1]=f2bf(w0a.y); xa0[2]=f2bf(w0a.z); xa0[3]=f2bf(w0a.w);
    xa0[4]=f2bf(w0b.x); xa0[5]=f2bf(w0b.y); xa0[6]=f2bf(w0b.z); xa0[7]=f2bf(w0b.w);
    xa1[0]=f2bf(w1a.x); xa1[1]=f2bf(w1a.y); xa1[2]=f2bf(w1a.z); xa1[3]=f2bf(w1a.w);
    xa1[4]=f2bf(w1b.x); xa1[5]=f2bf(w1b.y); xa1[6]=f2bf(w1b.z); xa1[7]=f2bf(w1b.w);

    float* myl = lds[wv];

    // ================= tile 0 =================
    {
        bf16x8 yf;
        yf[0]=f2bf(ba0.x); yf[1]=f2bf(ba0.y); yf[2]=f2bf(ba0.z); yf[3]=f2bf(ba0.w);
        yf[4]=f2bf(bb0.x); yf[5]=f2bf(bb0.y); yf[6]=f2bf(bb0.z); yf[7]=f2bf(bb0.w);
        f32x16 acc0 = {0,0,0,0, 0,0,0,0, 0,0,0,0, 0,0,0,0};
        f32x16 acc1 = {0,0,0,0, 0,0,0,0, 0,0,0,0, 0,0,0,0};
        acc0 = __builtin_amdgcn_mfma_f32_32x32x16_bf16(xa0, yf, acc0, 0, 0, 0);
        acc1 = __builtin_amdgcn_mfma_f32_32x32x16_bf16(xa1, yf, acc1, 0, 0, 0);

        if (ecc0 == 0) {
            // empty tile: direct register stores (no LDS round-trip)
            float* base = outv + (j0 + n) * DDIM + kh * 4;
#pragma unroll
            for (int q = 0; q < 4; ++q) {
                vfloat4 s0 = {acc0[4*q], acc0[4*q+1], acc0[4*q+2], acc0[4*q+3]};
                vfloat4 s1 = {acc1[4*q], acc1[4*q+1], acc1[4*q+2], acc1[4*q+3]};
                *reinterpret_cast<vfloat4*>(base + 8*q)      = s0;
                *reinterpret_cast<vfloat4*>(base + 8*q + 32) = s1;
            }
        } else {
#pragma unroll
            for (int q = 0; q < 4; ++q) {
                vfloat4 s0 = {acc0[4*q], acc0[4*q+1], acc0[4*q+2], acc0[4*q+3]};
                vfloat4 s1 = {acc1[4*q], acc1[4*q+1], acc1[4*q+2], acc1[4*q+3]};
                *reinterpret_cast<vfloat4*>(myl + n * LSTR + 8*q + 4*kh)      = s0;
                *reinterpret_cast<vfloat4*>(myl + n * LSTR + 32 + 8*q + 4*kh) = s1;
            }
#pragma unroll
            for (int i = 0; i < PF; ++i)
                if ((unsigned)i < ep0) myl[(pk0[i] & 31) * LSTR + l] += vpre0[i];
            for (unsigned i = PF; i < ecc0; ++i) {     // rare tail
                int packed = list[(long)tile0 * CAP + i];
                myl[(packed & 31) * LSTR + l] += ea[(long)(packed >> 5) * DDIM + l];
            }
#pragma unroll
            for (int i = 0; i < 8; ++i) {
                int row  = 4*i + (l >> 4);
                int colf = (l & 15) * 4;
                vfloat4 v = *reinterpret_cast<const vfloat4*>(myl + row * LSTR + colf);
                *reinterpret_cast<vfloat4*>(outv + (j0 + row) * DDIM + colf) = v;
            }
        }
    }

    // ================= tile 1 =================
    {
        bf16x8 yf;
        yf[0]=f2bf(ba1.x); yf[1]=f2bf(ba1.y); yf[2]=f2bf(ba1.z); yf[3]=f2bf(ba1.w);
        yf[4]=f2bf(bb1.x); yf[5]=f2bf(bb1.y); yf[6]=f2bf(bb1.z); yf[7]=f2bf(bb1.w);
        f32x16 acc0 = {0,0,0,0, 0,0,0,0, 0,0,0,0, 0,0,0,0};
        f32x16 acc1 = {0,0,0,0, 0,0,0,0, 0,0,0,0, 0,0,0,0};
        acc0 = __builtin_amdgcn_mfma_f32_32x32x16_bf16(xa0, yf, acc0, 0, 0, 0);
        acc1 = __builtin_amdgcn_mfma_f32_32x32x16_bf16(xa1, yf, acc1, 0, 0, 0);

        if (ecc1 == 0) {
            float* base = outv + (j0 + 32 + n) * DDIM + kh * 4;
#pragma unroll
            for (int q = 0; q < 4; ++q) {
                vfloat4 s0 = {acc0[4*q], acc0[4*q+1], acc0[4*q+2], acc0[4*q+3]};
                vfloat4 s1 = {acc1[4*q], acc1[4*q+1], acc1[4*q+2], acc1[4*q+3]};
                *reinterpret_cast<vfloat4*>(base + 8*q)      = s0;
                *reinterpret_cast<vfloat4*>(base + 8*q + 32) = s1;
            }
        } else {
#pragma unroll
            for (int q = 0; q < 4; ++q) {
                vfloat4 s0 = {acc0[4*q], acc0[4*q+1], acc0[4*q+2], acc0[4*q+3]};
                vfloat4 s1 = {acc1[4*q], acc1[4*q+1], acc1[4*q+2], acc1[4*q+3]};
                *reinterpret_cast<vfloat4*>(myl + n * LSTR + 8*q + 4*kh)      = s0;
                *reinterpret_cast<vfloat4*>(myl + n * LSTR + 32 + 8*q + 4*kh) = s1;
            }
#pragma unroll
            for (int i = 0; i < PF; ++i)
                if ((unsigned)i < ep1) myl[(pk1[i] & 31) * LSTR + l] += vpre1[i];
            for (unsigned i = PF; i < ecc1; ++i) {     // rare tail
                int packed = list[(long)(tile0 + 1) * CAP + i];
                myl[(packed & 31) * LSTR + l] += ea[(long)(packed >> 5) * DDIM + l];
            }
#pragma unroll
            for (int i = 0; i < 8; ++i) {
                int row  = 4*i + (l >> 4);
                int colf = (l & 15) * 4;
                vfloat4 v = *reinterpret_cast<const vfloat4*>(myl + row * LSTR + colf);
                *reinterpret_cast<vfloat4*>(outv + (j0 + 32 + row) * DDIM + colf) = v;
            }
        }
    }
}

// ---------------------------------------------------------------------------
__global__ __launch_bounds__(256) void ovf_fix(const float* __restrict__ ea,
                                               const int* __restrict__ ei,
                                               const unsigned* __restrict__ ovfc,
                                               const int* __restrict__ ovfl,
                                               float* __restrict__ outv) {
    unsigned nov = *ovfc;
    for (unsigned i = blockIdx.x * 256 + threadIdx.x; i < nov; i += 4 * 256) {
        int e = ovfl[i];
        long slot = edge_slot(ei, e);
        float* dst = outv + slot * DDIM;
        const float* src = ea + (long)e * DDIM;
        for (int j = 0; j < DDIM; ++j) unsafeAtomicAdd(dst + j, src[j]);
    }
}

// ---------------------------------------------------------------------------
// Fallback: proven separate path when ws too small.
// ---------------------------------------------------------------------------
__global__ __launch_bounds__(256) void pv_gemm(const float* __restrict__ pv,
                                               const float* __restrict__ W,
                                               float* __restrict__ outv) {
    __shared__ float lds[4][32 * LSTR];
    int tid = threadIdx.x;
    int wv  = tid >> 6;
    int l   = tid & 63;
    int n   = l & 31;
    int kh  = l >> 5;
    long j0 = ((long)blockIdx.x * 4 + wv) * (32 * TPW);

    const float4* wp0 = reinterpret_cast<const float4*>(W + n * KDIM + kh * 8);
    const float4* wp1 = reinterpret_cast<const float4*>(W + (32 + n) * KDIM + kh * 8);
    float4 w0a = wp0[0], w0b = wp0[1], w1a = wp1[0], w1b = wp1[1];
    bf16x8 xa0, xa1;
    xa0[0]=f2bf(w0a.x); xa0[1]=f2bf(w0a.y); xa0[2]=f2bf(w0a.z); xa0[3]=f2bf(w0a.w);
    xa0[4]=f2bf(w0b.x); xa0[5]=f2bf(w0b.y); xa0[6]=f2bf(w0b.z); xa0[7]=f2bf(w0b.w);
    xa1[0]=f2bf(w1a.x); xa1[1]=f2bf(w1a.y); xa1[2]=f2bf(w1a.z); xa1[3]=f2bf(w1a.w);
    xa1[4]=f2bf(w1b.x); xa1[5]=f2bf(w1b.y); xa1[6]=f2bf(w1b.z); xa1[7]=f2bf(w1b.w);

    float* myl = lds[wv];
#pragma unroll
    for (int t = 0; t < TPW; ++t) {
        long jt = j0 + t * 32;
        const float4* bp = reinterpret_cast<const float4*>(pv + (jt + n) * KDIM + kh * 8);
        float4 ba = bp[0], bb = bp[1];
        bf16x8 yf;
        yf[0]=f2bf(ba.x); yf[1]=f2bf(ba.y); yf[2]=f2bf(ba.z); yf[3]=f2bf(ba.w);
        yf[4]=f2bf(bb.x); yf[5]=f2bf(bb.y); yf[6]=f2bf(bb.z); yf[7]=f2bf(bb.w);

        f32x16 acc0 = {0,0,0,0, 0,0,0,0, 0,0,0,0, 0,0,0,0};
        f32x16 acc1 = {0,0,0,0, 0,0,0,0, 0,0,0,0, 0,0,0,0};
        acc0 = __builtin_amdgcn_mfma_f32_32x32x16_bf16(xa0, yf, acc0, 0, 0, 0);
        acc1 = __builtin_amdgcn_mfma_f32_32x32x16_bf16(xa1, yf, acc1, 0, 0, 0);
#pragma unroll
        for (int q = 0; q < 4; ++q) {
            vfloat4 s0 = {acc0[4*q], acc0[4*q+1], acc0[4*q+2], acc0[4*q+3]};
            vfloat4 s1 = {acc1[4*q], acc1[4*q+1], acc1[4*q+2], acc1[4*q+3]};
            *reinterpret_cast<vfloat4*>(myl + n * LSTR + 8*q + 4*kh)      = s0;
            *reinterpret_cast<vfloat4*>(myl + n * LSTR + 32 + 8*q + 4*kh) = s1;
        }
#pragma unroll
        for (int i = 0; i < 8; ++i) {
            int row  = 4*i + (l >> 4);
            int colf = (l & 15) * 4;
            vfloat4 v = *reinterpret_cast<const vfloat4*>(myl + row * LSTR + colf);
            *reinterpret_cast<vfloat4*>(outv + (jt + row) * DDIM + colf) = v;
        }
    }
}

__global__ __launch_bounds__(256) void fill_idx_plain(float* __restrict__ out) {
    int gid = blockIdx.x * 256 + threadIdx.x;
    int j0 = gid << 2;
    vfloat4 rv, cv;
#pragma unroll
    for (int i = 0; i < 4; ++i) {
        int j = j0 + i;
        int g = j >> 12;
        int rem = j & 4095;
        rv[i] = (float)((g << 6) + (rem >> 6));
        cv[i] = (float)((g << 6) + (rem & 63));
    }
    *reinterpret_cast<vfloat4*>(out + j0)      = rv;
    *reinterpret_cast<vfloat4*>(out + EF + j0) = cv;
}

__global__ __launch_bounds__(256) void scatter_edges(const float* __restrict__ ea,
                                                     const int* __restrict__ ei,
                                                     float* __restrict__ outv) {
    int gid = blockIdx.x * 256 + threadIdx.x;
    int e = gid >> 4;
    int t = gid & 15;
    long slot = edge_slot(ei, e);
    float4 v = *reinterpret_cast<const float4*>(ea + (long)e * DDIM + t * 4);
    float* dst = outv + slot * DDIM + t * 4;
    unsafeAtomicAdd(dst + 0, v.x);
    unsafeAtomicAdd(dst + 1, v.y);
    unsafeAtomicAdd(dst + 2, v.z);
    unsafeAtomicAdd(dst + 3, v.w);
}

extern "C" void kernel_launch(void* const* d_in, const int* in_sizes, int n_in,
                              void* d_out, int out_size, void* d_ws, size_t ws_size,
                              hipStream_t stream) {
    const float* poly_val  = (const float*)d_in[0];
    const float* edge_attr = (const float*)d_in[1];
    const float* W         = (const float*)d_in[2];
    const int*   edge_index = (const int*)d_in[4];

    float* out  = (float*)d_out;
    float* outv = out + 2 * (long)EF;

    if (ws_size >= (size_t)WS_NEED) {
        char* ws = (char*)d_ws;
        unsigned* cnt  = (unsigned*)(ws + WS_CNT_OFF);
        int*      list = (int*)     (ws + WS_LIST_OFF);
        unsigned* ovfc = (unsigned*)(ws + WS_OVFC_OFF);
        int*      ovfl = (int*)     (ws + WS_OVFL_OFF);

        zero_cnt<<<NTILE / 256, 256, 0, stream>>>(cnt, ovfc);
        bin_edges<<<NEDGE / 256, 256, 0, stream>>>(edge_index, cnt, list, ovfc, ovfl);
        pv_fused<<<PVBLK, 256, 0, stream>>>(poly_val, W, edge_attr, cnt, list, out, outv);
        ovf_fix<<<4, 256, 0, stream>>>(edge_attr, edge_index, ovfc, ovfl, outv);
    } else {
        fill_idx_plain<<<EF / 4 / 256, 256, 0, stream>>>(out);
        pv_gemm<<<PVBLK, 256, 0, stream>>>(poly_val, W, outv);
        scatter_edges<<<(NEDGE * 16) / 256, 256, 0, stream>>>(edge_attr, edge_index, outv);
    }
}

// Round 26
// 45.026 us; speedup vs baseline: 1.0290x; 1.0290x over previous
//
#include <hip/hip_runtime.h>

// Problem constants: B=128, n=64, E=65536, K=16, D=64, e_full=524288
#define EF      524288
#define NEDGE   65536
#define KDIM    16
#define DDIM    64
#define TPW     2
#define PVBLK   (EF / (32 * TPW) / 4)   // 2048 blocks, 4 waves each
#define LSTR    68
#define NTILE   (EF / 32)               // 16384 slot-tiles of 32 rows
#define CAP     64                      // edge-list capacity per tile (avg 4)
#define PF      8                       // edge rows prefetched per tile

typedef float vfloat4 __attribute__((ext_vector_type(4)));
typedef short bf16x8  __attribute__((ext_vector_type(8)));
typedef float f32x16  __attribute__((ext_vector_type(16)));

__device__ __forceinline__ short f2bf(float f) {   // f32 -> bf16, RNE
    unsigned u = __float_as_uint(f);
    return (short)((u + 0x7FFFu + ((u >> 16) & 1u)) >> 16);
}

__device__ __forceinline__ long edge_slot(const int* ei, int e) {
    int r = ei[e];
    int c = ei[NEDGE + e];
    return ((long)(r >> 6) << 12) + ((long)(r & 63) << 6) + (long)(c & 63);
}

// ws layout: [0,64K) tile counts | [64K,64K+4M) lists | ovf_cnt | ovf list
#define WS_CNT_OFF   0
#define WS_LIST_OFF  (64 * 1024)
#define WS_OVFC_OFF  (WS_LIST_OFF + NTILE * CAP * 4)
#define WS_OVFL_OFF  (WS_OVFC_OFF + 4)
#define WS_NEED      (WS_OVFL_OFF + NEDGE * 4)

// ---------------------------------------------------------------------------
__global__ __launch_bounds__(256) void zero_cnt(unsigned* __restrict__ cnt,
                                                unsigned* __restrict__ ovfc) {
    int gid = blockIdx.x * 256 + threadIdx.x;   // 16384 threads
    cnt[gid] = 0u;
    if (gid == 0) *ovfc = 0u;
}

// ---------------------------------------------------------------------------
__global__ __launch_bounds__(256) void bin_edges(const int* __restrict__ ei,
                                                 unsigned* __restrict__ cnt,
                                                 int* __restrict__ list,
                                                 unsigned* __restrict__ ovfc,
                                                 int* __restrict__ ovfl) {
    int e = blockIdx.x * 256 + threadIdx.x;     // NEDGE threads
    long slot = edge_slot(ei, e);
    int tile = (int)(slot >> 5);
    int row  = (int)(slot & 31);
    unsigned pos = atomicAdd(&cnt[tile], 1u);
    if (pos < CAP) list[tile * CAP + pos] = (e << 5) | row;
    else           ovfl[atomicAdd(ovfc, 1u)] = e;
}

// ---------------------------------------------------------------------------
// pv_fused v5 (session best, 45.14us):
//  * ea prefetch UNCONDITIONAL with clamped edge index ((u>>5)&65535) --
//    breaks the cnt->ea dependence; prologue = cnt || (list->ea) || pv || W.
//    Garbage entries past ec load in-bounds junk that is never consumed.
//  * idx-fill folded in: each block writes its 256 contiguous out floats
//    in the latency shadow between load-issue and MFMA.
//  * per-wave LDS tile for the coalesced binned edge adds; dense 1KB stores.
// ---------------------------------------------------------------------------
__global__ __launch_bounds__(256) void pv_fused(const float* __restrict__ pv,
                                                const float* __restrict__ W,
                                                const float* __restrict__ ea,
                                                const unsigned* __restrict__ cnt,
                                                const int* __restrict__ list,
                                                float* __restrict__ out,
                                                float* __restrict__ outv) {
    __shared__ float lds[4][32 * LSTR];
    int tid = threadIdx.x;
    int wv  = tid >> 6;
    int l   = tid & 63;
    int n   = l & 31;
    int kh  = l >> 5;
    long j0 = ((long)blockIdx.x * 4 + wv) * (32 * TPW);
    int tile0 = (int)(j0 >> 5);

    // ---- issue-early: cnt (2), list (16, unconditional) ----
    unsigned ec0 = cnt[tile0];
    unsigned ec1 = cnt[tile0 + 1];
    int pk0[PF], pk1[PF];
#pragma unroll
    for (int i = 0; i < PF; ++i) {
        pk0[i] = list[(long)tile0 * CAP + i];
        pk1[i] = list[(long)(tile0 + 1) * CAP + i];
    }

    // ---- idx fill for this block's 256 rows (independent; hides latency) ----
    {
        int j = blockIdx.x * 256 + tid;         // [0, EF)
        int g = j >> 12;
        int rem = j & 4095;
        out[j]      = (float)((g << 6) + (rem >> 6));
        out[EF + j] = (float)((g << 6) + (rem & 63));
    }

    // ---- ea rows: unconditional, index clamped in-bounds ----
    float vpre0[PF], vpre1[PF];
#pragma unroll
    for (int i = 0; i < PF; ++i) {
        unsigned e0 = ((unsigned)pk0[i] >> 5) & (NEDGE - 1);
        unsigned e1 = ((unsigned)pk1[i] >> 5) & (NEDGE - 1);
        vpre0[i] = ea[(long)e0 * DDIM + l];
        vpre1[i] = ea[(long)e1 * DDIM + l];
    }

    unsigned ecc0 = ec0 > CAP ? CAP : ec0;
    unsigned ecc1 = ec1 > CAP ? CAP : ec1;
    unsigned ep0 = ecc0 > PF ? PF : ecc0;
    unsigned ep1 = ecc1 > PF ? PF : ecc1;

    // ---- pv fragments (both tiles) ----
    const float4* bp0 = reinterpret_cast<const float4*>(pv + (j0 + n) * KDIM + kh * 8);
    const float4* bp1 = reinterpret_cast<const float4*>(pv + (j0 + 32 + n) * KDIM + kh * 8);
    float4 ba0 = bp0[0], bb0 = bp0[1], ba1 = bp1[0], bb1 = bp1[1];

    // ---- W fragments (L1-resident) ----
    const float4* wp0 = reinterpret_cast<const float4*>(W + n * KDIM + kh * 8);
    const float4* wp1 = reinterpret_cast<const float4*>(W + (32 + n) * KDIM + kh * 8);
    float4 w0a = wp0[0], w0b = wp0[1], w1a = wp1[0], w1b = wp1[1];
    bf16x8 xa0, xa1;
    xa0[0]=f2bf(w0a.x); xa0[1]=f2bf(w0a.y); xa0[2]=f2bf(w0a.z); xa0[3]=f2bf(w0a.w);
    xa0[4]=f2bf(w0b.x); xa0[5]=f2bf(w0b.y); xa0[6]=f2bf(w0b.z); xa0[7]=f2bf(w0b.w);
    xa1[0]=f2bf(w1a.x); xa1[1]=f2bf(w1a.y); xa1[2]=f2bf(w1a.z); xa1[3]=f2bf(w1a.w);
    xa1[4]=f2bf(w1b.x); xa1[5]=f2bf(w1b.y); xa1[6]=f2bf(w1b.z); xa1[7]=f2bf(w1b.w);

    float* myl = lds[wv];

    // ================= tile 0 =================
    {
        bf16x8 yf;
        yf[0]=f2bf(ba0.x); yf[1]=f2bf(ba0.y); yf[2]=f2bf(ba0.z); yf[3]=f2bf(ba0.w);
        yf[4]=f2bf(bb0.x); yf[5]=f2bf(bb0.y); yf[6]=f2bf(bb0.z); yf[7]=f2bf(bb0.w);
        f32x16 acc0 = {0,0,0,0, 0,0,0,0, 0,0,0,0, 0,0,0,0};
        f32x16 acc1 = {0,0,0,0, 0,0,0,0, 0,0,0,0, 0,0,0,0};
        acc0 = __builtin_amdgcn_mfma_f32_32x32x16_bf16(xa0, yf, acc0, 0, 0, 0);
        acc1 = __builtin_amdgcn_mfma_f32_32x32x16_bf16(xa1, yf, acc1, 0, 0, 0);
#pragma unroll
        for (int q = 0; q < 4; ++q) {
            vfloat4 s0 = {acc0[4*q], acc0[4*q+1], acc0[4*q+2], acc0[4*q+3]};
            vfloat4 s1 = {acc1[4*q], acc1[4*q+1], acc1[4*q+2], acc1[4*q+3]};
            *reinterpret_cast<vfloat4*>(myl + n * LSTR + 8*q + 4*kh)      = s0;
            *reinterpret_cast<vfloat4*>(myl + n * LSTR + 32 + 8*q + 4*kh) = s1;
        }
#pragma unroll
        for (int i = 0; i < PF; ++i)
            if ((unsigned)i < ep0) myl[(pk0[i] & 31) * LSTR + l] += vpre0[i];
        for (unsigned i = PF; i < ecc0; ++i) {     // rare tail
            int packed = list[(long)tile0 * CAP + i];
            myl[(packed & 31) * LSTR + l] += ea[(long)(packed >> 5) * DDIM + l];
        }
#pragma unroll
        for (int i = 0; i < 8; ++i) {
            int row  = 4*i + (l >> 4);
            int colf = (l & 15) * 4;
            vfloat4 v = *reinterpret_cast<const vfloat4*>(myl + row * LSTR + colf);
            *reinterpret_cast<vfloat4*>(outv + (j0 + row) * DDIM + colf) = v;
        }
    }

    // ================= tile 1 =================
    {
        bf16x8 yf;
        yf[0]=f2bf(ba1.x); yf[1]=f2bf(ba1.y); yf[2]=f2bf(ba1.z); yf[3]=f2bf(ba1.w);
        yf[4]=f2bf(bb1.x); yf[5]=f2bf(bb1.y); yf[6]=f2bf(bb1.z); yf[7]=f2bf(bb1.w);
        f32x16 acc0 = {0,0,0,0, 0,0,0,0, 0,0,0,0, 0,0,0,0};
        f32x16 acc1 = {0,0,0,0, 0,0,0,0, 0,0,0,0, 0,0,0,0};
        acc0 = __builtin_amdgcn_mfma_f32_32x32x16_bf16(xa0, yf, acc0, 0, 0, 0);
        acc1 = __builtin_amdgcn_mfma_f32_32x32x16_bf16(xa1, yf, acc1, 0, 0, 0);
#pragma unroll
        for (int q = 0; q < 4; ++q) {
            vfloat4 s0 = {acc0[4*q], acc0[4*q+1], acc0[4*q+2], acc0[4*q+3]};
            vfloat4 s1 = {acc1[4*q], acc1[4*q+1], acc1[4*q+2], acc1[4*q+3]};
            *reinterpret_cast<vfloat4*>(myl + n * LSTR + 8*q + 4*kh)      = s0;
            *reinterpret_cast<vfloat4*>(myl + n * LSTR + 32 + 8*q + 4*kh) = s1;
        }
#pragma unroll
        for (int i = 0; i < PF; ++i)
            if ((unsigned)i < ep1) myl[(pk1[i] & 31) * LSTR + l] += vpre1[i];
        for (unsigned i = PF; i < ecc1; ++i) {     // rare tail
            int packed = list[(long)(tile0 + 1) * CAP + i];
            myl[(packed & 31) * LSTR + l] += ea[(long)(packed >> 5) * DDIM + l];
        }
#pragma unroll
        for (int i = 0; i < 8; ++i) {
            int row  = 4*i + (l >> 4);
            int colf = (l & 15) * 4;
            vfloat4 v = *reinterpret_cast<const vfloat4*>(myl + row * LSTR + colf);
            *reinterpret_cast<vfloat4*>(outv + (j0 + 32 + row) * DDIM + colf) = v;
        }
    }
}

// ---------------------------------------------------------------------------
__global__ __launch_bounds__(256) void ovf_fix(const float* __restrict__ ea,
                                               const int* __restrict__ ei,
                                               const unsigned* __restrict__ ovfc,
                                               const int* __restrict__ ovfl,
                                               float* __restrict__ outv) {
    unsigned nov = *ovfc;
    for (unsigned i = blockIdx.x * 256 + threadIdx.x; i < nov; i += 4 * 256) {
        int e = ovfl[i];
        long slot = edge_slot(ei, e);
        float* dst = outv + slot * DDIM;
        const float* src = ea + (long)e * DDIM;
        for (int j = 0; j < DDIM; ++j) unsafeAtomicAdd(dst + j, src[j]);
    }
}

// ---------------------------------------------------------------------------
// Fallback: proven separate path when ws too small.
// ---------------------------------------------------------------------------
__global__ __launch_bounds__(256) void pv_gemm(const float* __restrict__ pv,
                                               const float* __restrict__ W,
                                               float* __restrict__ outv) {
    __shared__ float lds[4][32 * LSTR];
    int tid = threadIdx.x;
    int wv  = tid >> 6;
    int l   = tid & 63;
    int n   = l & 31;
    int kh  = l >> 5;
    long j0 = ((long)blockIdx.x * 4 + wv) * (32 * TPW);

    const float4* wp0 = reinterpret_cast<const float4*>(W + n * KDIM + kh * 8);
    const float4* wp1 = reinterpret_cast<const float4*>(W + (32 + n) * KDIM + kh * 8);
    float4 w0a = wp0[0], w0b = wp0[1], w1a = wp1[0], w1b = wp1[1];
    bf16x8 xa0, xa1;
    xa0[0]=f2bf(w0a.x); xa0[1]=f2bf(w0a.y); xa0[2]=f2bf(w0a.z); xa0[3]=f2bf(w0a.w);
    xa0[4]=f2bf(w0b.x); xa0[5]=f2bf(w0b.y); xa0[6]=f2bf(w0b.z); xa0[7]=f2bf(w0b.w);
    xa1[0]=f2bf(w1a.x); xa1[1]=f2bf(w1a.y); xa1[2]=f2bf(w1a.z); xa1[3]=f2bf(w1a.w);
    xa1[4]=f2bf(w1b.x); xa1[5]=f2bf(w1b.y); xa1[6]=f2bf(w1b.z); xa1[7]=f2bf(w1b.w);

    float* myl = lds[wv];
#pragma unroll
    for (int t = 0; t < TPW; ++t) {
        long jt = j0 + t * 32;
        const float4* bp = reinterpret_cast<const float4*>(pv + (jt + n) * KDIM + kh * 8);
        float4 ba = bp[0], bb = bp[1];
        bf16x8 yf;
        yf[0]=f2bf(ba.x); yf[1]=f2bf(ba.y); yf[2]=f2bf(ba.z); yf[3]=f2bf(ba.w);
        yf[4]=f2bf(bb.x); yf[5]=f2bf(bb.y); yf[6]=f2bf(bb.z); yf[7]=f2bf(bb.w);

        f32x16 acc0 = {0,0,0,0, 0,0,0,0, 0,0,0,0, 0,0,0,0};
        f32x16 acc1 = {0,0,0,0, 0,0,0,0, 0,0,0,0, 0,0,0,0};
        acc0 = __builtin_amdgcn_mfma_f32_32x32x16_bf16(xa0, yf, acc0, 0, 0, 0);
        acc1 = __builtin_amdgcn_mfma_f32_32x32x16_bf16(xa1, yf, acc1, 0, 0, 0);
#pragma unroll
        for (int q = 0; q < 4; ++q) {
            vfloat4 s0 = {acc0[4*q], acc0[4*q+1], acc0[4*q+2], acc0[4*q+3]};
            vfloat4 s1 = {acc1[4*q], acc1[4*q+1], acc1[4*q+2], acc1[4*q+3]};
            *reinterpret_cast<vfloat4*>(myl + n * LSTR + 8*q + 4*kh)      = s0;
            *reinterpret_cast<vfloat4*>(myl + n * LSTR + 32 + 8*q + 4*kh) = s1;
        }
#pragma unroll
        for (int i = 0; i < 8; ++i) {
            int row  = 4*i + (l >> 4);
            int colf = (l & 15) * 4;
            vfloat4 v = *reinterpret_cast<const vfloat4*>(myl + row * LSTR + colf);
            *reinterpret_cast<vfloat4*>(outv + (jt + row) * DDIM + colf) = v;
        }
    }
}

__global__ __launch_bounds__(256) void fill_idx_plain(float* __restrict__ out) {
    int gid = blockIdx.x * 256 + threadIdx.x;
    int j0 = gid << 2;
    vfloat4 rv, cv;
#pragma unroll
    for (int i = 0; i < 4; ++i) {
        int j = j0 + i;
        int g = j >> 12;
        int rem = j & 4095;
        rv[i] = (float)((g << 6) + (rem >> 6));
        cv[i] = (float)((g << 6) + (rem & 63));
    }
    *reinterpret_cast<vfloat4*>(out + j0)      = rv;
    *reinterpret_cast<vfloat4*>(out + EF + j0) = cv;
}

__global__ __launch_bounds__(256) void scatter_edges(const float* __restrict__ ea,
                                                     const int* __restrict__ ei,
                                                     float* __restrict__ outv) {
    int gid = blockIdx.x * 256 + threadIdx.x;
    int e = gid >> 4;
    int t = gid & 15;
    long slot = edge_slot(ei, e);
    float4 v = *reinterpret_cast<const float4*>(ea + (long)e * DDIM + t * 4);
    float* dst = outv + slot * DDIM + t * 4;
    unsafeAtomicAdd(dst + 0, v.x);
    unsafeAtomicAdd(dst + 1, v.y);
    unsafeAtomicAdd(dst + 2, v.z);
    unsafeAtomicAdd(dst + 3, v.w);
}

extern "C" void kernel_launch(void* const* d_in, const int* in_sizes, int n_in,
                              void* d_out, int out_size, void* d_ws, size_t ws_size,
                              hipStream_t stream) {
    const float* poly_val  = (const float*)d_in[0];
    const float* edge_attr = (const float*)d_in[1];
    const float* W         = (const float*)d_in[2];
    const int*   edge_index = (const int*)d_in[4];

    float* out  = (float*)d_out;
    float* outv = out + 2 * (long)EF;

    if (ws_size >= (size_t)WS_NEED) {
        char* ws = (char*)d_ws;
        unsigned* cnt  = (unsigned*)(ws + WS_CNT_OFF);
        int*      list = (int*)     (ws + WS_LIST_OFF);
        unsigned* ovfc = (unsigned*)(ws + WS_OVFC_OFF);
        int*      ovfl = (int*)     (ws + WS_OVFL_OFF);

        zero_cnt<<<NTILE / 256, 256, 0, stream>>>(cnt, ovfc);
        bin_edges<<<NEDGE / 256, 256, 0, stream>>>(edge_index, cnt, list, ovfc, ovfl);
        pv_fused<<<PVBLK, 256, 0, stream>>>(poly_val, W, edge_attr, cnt, list, out, outv);
        ovf_fix<<<4, 256, 0, stream>>>(edge_attr, edge_index, ovfc, ovfl, outv);
    } else {
        fill_idx_plain<<<EF / 4 / 256, 256, 0, stream>>>(out);
        pv_gemm<<<PVBLK, 256, 0, stream>>>(poly_val, W, outv);
        scatter_edges<<<(NEDGE * 16) / 256, 256, 0, stream>>>(edge_attr, edge_index, outv);
    }
}